// Round 1
// baseline (554.835 us; speedup 1.0000x reference)
//
#include <hip/hip_runtime.h>

// GraphConvGRU: B=16384, IN=32, HID=3, N=22 nodes, T=100 steps.
// Key insight: the fixed graph has 3 node-equivalence classes:
//   C0={0,9}(deg13), C1=16 clique-private nodes (deg4), C2={3,6,12,15}(deg5).
// h stays class-uniform (h0=0, x-projections broadcast over nodes), so the
// per-batch state is 3 classes x 3 hid = 9 floats and the 22x22 normalized
// adjacency reduces exactly to a 3x3 matrix M (verified row-by-row).
// Kernel: thread = one batch element, runs the 100-step recurrence in
// registers; states staged to LDS (double-buffered) and expanded to the
// 22-node layout with cooperative, fully-coalesced float4 stores.

#define TPB 256
#define GRID 64                     // 16384 / 256
#define T_TOTAL 100
#define SCH 2                       // steps per chunk
#define NCHUNK (T_TOTAL / SCH)      // 50
#define ROW_F4 33                   // float4 per (thread-row, chunk): SCH*66/4
#define STG_STRIDE 19               // padded floats per thread-row (SCH*9 + 1)
#define STG_SZ (TPB * STG_STRIDE)   // 4864 floats per buffer

#if __has_builtin(__builtin_amdgcn_exp2f)
#define EXP2F __builtin_amdgcn_exp2f
#else
#define EXP2F exp2f
#endif
#if __has_builtin(__builtin_amdgcn_rcpf)
#define RCPF __builtin_amdgcn_rcpf
#else
#define RCPF(x) (1.0f / (x))
#endif

static __device__ __forceinline__ float fast_sigmoid(float x) {
    float e = EXP2F(-1.44269504f * x);
    return RCPF(1.0f + e);
}
static __device__ __forceinline__ float fast_tanh(float x) {
    float e = EXP2F(2.88539008f * x);          // exp(2x)
    return 1.0f - 2.0f * RCPF(1.0f + e);
}

__global__ __launch_bounds__(TPB, 1) void gcgru_kernel(
    const float* __restrict__ x,
    const float* __restrict__ w_r_W, const float* __restrict__ w_r_b,
    const float* __restrict__ w_z_W, const float* __restrict__ w_z_b,
    const float* __restrict__ w_h_W, const float* __restrict__ w_h_b,
    const float* __restrict__ gcn_W, const float* __restrict__ gcn_b,
    float* __restrict__ out)
{
    __shared__ float wS[297];           // w_r_W[96], w_z_W[96], w_h_W[96], biases r/z/h [9]
    __shared__ float gwS[9];
    __shared__ float gbS[3];
    __shared__ unsigned int tabS[ROW_F4];   // packed per-float4 LDS offsets
    __shared__ float stage[2 * STG_SZ];     // double-buffered compact states

    const int tid = threadIdx.x;
    const int b0  = blockIdx.x * TPB;

    // ---- one-time: stage weights + build expansion table ----
    if (tid < 96) {
        wS[tid]       = w_r_W[tid];
        wS[96 + tid]  = w_z_W[tid];
        wS[192 + tid] = w_h_W[tid];
    }
    if (tid < 3) {
        wS[288 + tid] = w_r_b[tid];
        wS[291 + tid] = w_z_b[tid];
        wS[294 + tid] = w_h_b[tid];
        gbS[tid] = gcn_b[tid];
    }
    if (tid < 9) gwS[tid] = gcn_W[tid];
    if (tid < ROW_F4) {
        // cls3[k] = class(node k/3)*3 + k%3 for k in [0,66)
        static const unsigned char cls3[66] = {
            0,1,2, 3,4,5, 3,4,5, 6,7,8, 3,4,5, 3,4,5, 6,7,8, 3,4,5, 3,4,5,
            0,1,2, 3,4,5, 3,4,5, 6,7,8, 3,4,5, 3,4,5, 6,7,8, 3,4,5, 3,4,5,
            3,4,5, 3,4,5, 3,4,5, 3,4,5
        };
        int j = 4 * tid;
        unsigned int w = 0;
        #pragma unroll
        for (int u = 0; u < 4; ++u) {
            int jj = j + u;              // 0..131 within a 2-step row
            int tl = jj / 66;            // local step 0/1
            int k  = jj - 66 * tl;       // 0..65
            w |= (unsigned int)(tl * 9 + cls3[k]) << (8 * u);
        }
        tabS[tid] = w;
    }
    __syncthreads();

    // ---- per-batch input projections: xr/xz/xh = x @ W + b ----
    float xv[32];
    {
        const float4* xp = reinterpret_cast<const float4*>(x + (size_t)(b0 + tid) * 32);
        #pragma unroll
        for (int i = 0; i < 8; ++i) {
            float4 v = xp[i];
            xv[4*i+0] = v.x; xv[4*i+1] = v.y; xv[4*i+2] = v.z; xv[4*i+3] = v.w;
        }
    }
    float xr[3], xz[3], xh[3];
    #pragma unroll
    for (int j = 0; j < 3; ++j) { xr[j] = wS[288+j]; xz[j] = wS[291+j]; xh[j] = wS[294+j]; }
    #pragma unroll
    for (int i = 0; i < 32; ++i) {
        float xi = xv[i];
        #pragma unroll
        for (int j = 0; j < 3; ++j) {
            xr[j] = fmaf(xi, wS[i*3+j],       xr[j]);
            xz[j] = fmaf(xi, wS[96 + i*3+j],  xz[j]);
            xh[j] = fmaf(xi, wS[192 + i*3+j], xh[j]);
        }
    }

    float W9[9], gb3[3];
    #pragma unroll
    for (int i = 0; i < 9; ++i) W9[i] = gwS[i];
    #pragma unroll
    for (int j = 0; j < 3; ++j) gb3[j] = gbS[j];

    // reduced symmetric-normalized adjacency (3 classes), exact:
    const float M00 = 0.0769230769f;   // 1/13
    const float M01 = 1.1094003925f;   // 4/sqrt(13)
    const float M02 = 0.4961389384f;   // 4/sqrt(65)
    const float M10 = 0.1386750491f;   // 1/(2 sqrt(13))
    const float M11 = 0.75f;
    const float M20 = 0.2480694691f;   // 2/sqrt(65)
    const float M22 = 0.6f;

    float h[9];
    #pragma unroll
    for (int i = 0; i < 9; ++i) h[i] = 0.0f;

    float4* out4 = reinterpret_cast<float4*>(out);

    for (int chunk = 0; chunk < NCHUNK; ++chunk) {
        float* stw = stage + (chunk & 1) * STG_SZ + tid * STG_STRIDE;

        #pragma unroll
        for (int s = 0; s < SCH; ++s) {
            float mh[9], gh[9];
            #pragma unroll
            for (int j = 0; j < 3; ++j) {
                mh[j]     = M00 * h[j] + M01 * h[3+j] + M02 * h[6+j];
                mh[3 + j] = M10 * h[j] + M11 * h[3+j];
                mh[6 + j] = M20 * h[j] + M22 * h[6+j];
            }
            #pragma unroll
            for (int c = 0; c < 3; ++c)
                #pragma unroll
                for (int j = 0; j < 3; ++j)
                    gh[c*3+j] = gb3[j] + mh[c*3+0]*W9[j] + mh[c*3+1]*W9[3+j] + mh[c*3+2]*W9[6+j];
            #pragma unroll
            for (int c = 0; c < 3; ++c) {
                #pragma unroll
                for (int j = 0; j < 3; ++j) {
                    float g  = gh[c*3+j];
                    float r  = fast_sigmoid(xr[j] + g);
                    float z  = fast_sigmoid(xz[j] + g);
                    float ht = fast_tanh(xh[j] + r * g);
                    float hv = h[c*3+j];
                    h[c*3+j] = hv + z * (ht - hv);
                }
            }
            #pragma unroll
            for (int q = 0; q < 9; ++q) stw[s*9 + q] = h[q];
        }

        __syncthreads();   // stage buffer (chunk&1) complete for all threads

        // cooperative coalesced expansion: 256 rows x 33 float4 each
        const float* str = stage + (chunk & 1) * STG_SZ;
        const int c33 = chunk * 33;
        for (int i = 0; i < ROW_F4; ++i) {
            int f  = i * TPB + tid;          // 0..8447
            int r  = f / 33;                 // row (batch element within block)
            int j4 = f - r * 33;             // float4 index within row
            unsigned int tw = tabS[j4];
            const float* row = str + r * STG_STRIDE;
            float4 v;
            v.x = row[tw & 255u];
            v.y = row[(tw >> 8)  & 255u];
            v.z = row[(tw >> 16) & 255u];
            v.w = row[tw >> 24];
            out4[(size_t)(b0 + r) * 1650 + c33 + j4] = v;
        }
        // no trailing barrier: next chunk computes into the other buffer;
        // the next leading barrier orders coop-reads(c) vs compute-writes(c+2)
    }
}

extern "C" void kernel_launch(void* const* d_in, const int* in_sizes, int n_in,
                              void* d_out, int out_size, void* d_ws, size_t ws_size,
                              hipStream_t stream) {
    const float* xp     = (const float*)d_in[0];
    const float* w_r_W  = (const float*)d_in[1];
    const float* w_r_b  = (const float*)d_in[2];
    const float* w_z_W  = (const float*)d_in[3];
    const float* w_z_b  = (const float*)d_in[4];
    const float* w_h_W  = (const float*)d_in[5];
    const float* w_h_b  = (const float*)d_in[6];
    const float* gcn_W  = (const float*)d_in[7];
    const float* gcn_b  = (const float*)d_in[8];
    float* outp = (float*)d_out;

    gcgru_kernel<<<GRID, TPB, 0, stream>>>(xp, w_r_W, w_r_b, w_z_W, w_z_b,
                                           w_h_W, w_h_b, gcn_W, gcn_b, outp);
}

// Round 2
// 537.194 us; speedup vs baseline: 1.0328x; 1.0328x over previous
//
#include <hip/hip_runtime.h>

// GraphConvGRU: B=16384, IN=32, HID=3, N=22 nodes, T=100 steps.
// Graph collapses to 3 node-equivalence classes -> per-chain state is 9 floats,
// 22x22 normalized adjacency reduces exactly to 3x3 (verified row-by-row; R0
// passed with absmax 3.9e-3).
//
// R1 change: store-parallelism via compute replication.
//   R0 used 64 blocks x 256 thr = 64 CUs -> ~1.5 TB/s store ceiling -> 554 us.
//   Now 1024 blocks x 64 thr: 4 replica blocks per 64-chain group, each
//   redundantly computes the recurrence (cheap, ~31 us/wave, parallel across
//   the 4 SIMDs of a CU) and stores 1/4 of the output f4s. All 256 CUs store
//   => fillBuffer-regime write BW (6 TB/s @ 10% occupancy per R0 profile).

#define TPB 64
#define REP 4
#define NGRP (16384 / TPB)          // 256 chain-groups
#define GRID (NGRP * REP)           // 1024 blocks
#define T_TOTAL 100
#define SCH 2                       // steps per chunk
#define NCHUNK (T_TOTAL / SCH)      // 50
#define ROW_F4 33                   // float4 per (row, chunk): SCH*66/4
#define STG_STRIDE 19               // padded floats per row (SCH*9 + 1)
#define STG_SZ (TPB * STG_STRIDE)   // 1216 floats per buffer

#if __has_builtin(__builtin_amdgcn_exp2f)
#define EXP2F __builtin_amdgcn_exp2f
#else
#define EXP2F exp2f
#endif
#if __has_builtin(__builtin_amdgcn_rcpf)
#define RCPF __builtin_amdgcn_rcpf
#else
#define RCPF(x) (1.0f / (x))
#endif

static __device__ __forceinline__ float fast_sigmoid(float x) {
    float e = EXP2F(-1.44269504f * x);
    return RCPF(1.0f + e);
}
static __device__ __forceinline__ float fast_tanh(float x) {
    float e = EXP2F(2.88539008f * x);          // exp(2x)
    return 1.0f - 2.0f * RCPF(1.0f + e);
}

__global__ __launch_bounds__(TPB) void gcgru_kernel(
    const float* __restrict__ x,
    const float* __restrict__ w_r_W, const float* __restrict__ w_r_b,
    const float* __restrict__ w_z_W, const float* __restrict__ w_z_b,
    const float* __restrict__ w_h_W, const float* __restrict__ w_h_b,
    const float* __restrict__ gcn_W, const float* __restrict__ gcn_b,
    float* __restrict__ out)
{
    __shared__ float wS[297];           // w_r_W[96], w_z_W[96], w_h_W[96], biases r/z/h [9]
    __shared__ float gwS[9];
    __shared__ float gbS[3];
    __shared__ unsigned int tabS[ROW_F4];   // packed per-float4 LDS offsets
    __shared__ float stage[2 * STG_SZ];     // double-buffered compact states

    const int tid = threadIdx.x;            // 0..63, chain within group
    const int rep = blockIdx.x & (REP - 1); // replica id 0..3
    const int b0  = (blockIdx.x >> 2) * TPB;

    // ---- one-time: stage weights + build expansion table ----
    for (int i = tid; i < 96; i += TPB) {
        wS[i]       = w_r_W[i];
        wS[96 + i]  = w_z_W[i];
        wS[192 + i] = w_h_W[i];
    }
    if (tid < 3) {
        wS[288 + tid] = w_r_b[tid];
        wS[291 + tid] = w_z_b[tid];
        wS[294 + tid] = w_h_b[tid];
        gbS[tid] = gcn_b[tid];
    }
    if (tid < 9) gwS[tid] = gcn_W[tid];
    if (tid < ROW_F4) {
        // cls3[k] = class(node k/3)*3 + k%3 for k in [0,66)
        static const unsigned char cls3[66] = {
            0,1,2, 3,4,5, 3,4,5, 6,7,8, 3,4,5, 3,4,5, 6,7,8, 3,4,5, 3,4,5,
            0,1,2, 3,4,5, 3,4,5, 6,7,8, 3,4,5, 3,4,5, 6,7,8, 3,4,5, 3,4,5,
            3,4,5, 3,4,5, 3,4,5, 3,4,5
        };
        int j = 4 * tid;
        unsigned int w = 0;
        #pragma unroll
        for (int u = 0; u < 4; ++u) {
            int jj = j + u;              // 0..131 within a 2-step row
            int tl = jj / 66;            // local step 0/1
            int k  = jj - 66 * tl;       // 0..65
            w |= (unsigned int)(tl * 9 + cls3[k]) << (8 * u);
        }
        tabS[tid] = w;
    }
    __syncthreads();

    // ---- per-chain input projections: xr/xz/xh = x @ W + b ----
    float xv[32];
    {
        const float4* xp = reinterpret_cast<const float4*>(x + (size_t)(b0 + tid) * 32);
        #pragma unroll
        for (int i = 0; i < 8; ++i) {
            float4 v = xp[i];
            xv[4*i+0] = v.x; xv[4*i+1] = v.y; xv[4*i+2] = v.z; xv[4*i+3] = v.w;
        }
    }
    float xr[3], xz[3], xh[3];
    #pragma unroll
    for (int j = 0; j < 3; ++j) { xr[j] = wS[288+j]; xz[j] = wS[291+j]; xh[j] = wS[294+j]; }
    #pragma unroll
    for (int i = 0; i < 32; ++i) {
        float xi = xv[i];
        #pragma unroll
        for (int j = 0; j < 3; ++j) {
            xr[j] = fmaf(xi, wS[i*3+j],       xr[j]);
            xz[j] = fmaf(xi, wS[96 + i*3+j],  xz[j]);
            xh[j] = fmaf(xi, wS[192 + i*3+j], xh[j]);
        }
    }

    float W9[9], gb3[3];
    #pragma unroll
    for (int i = 0; i < 9; ++i) W9[i] = gwS[i];
    #pragma unroll
    for (int j = 0; j < 3; ++j) gb3[j] = gbS[j];

    // reduced symmetric-normalized adjacency (3 classes), exact:
    const float M00 = 0.0769230769f;   // 1/13
    const float M01 = 1.1094003925f;   // 4/sqrt(13)
    const float M02 = 0.4961389384f;   // 4/sqrt(65)
    const float M10 = 0.1386750491f;   // 1/(2 sqrt(13))
    const float M11 = 0.75f;
    const float M20 = 0.2480694691f;   // 2/sqrt(65)
    const float M22 = 0.6f;

    float h[9];
    #pragma unroll
    for (int i = 0; i < 9; ++i) h[i] = 0.0f;

    float4* out4 = reinterpret_cast<float4*>(out);

    for (int chunk = 0; chunk < NCHUNK; ++chunk) {
        float* stw = stage + (chunk & 1) * STG_SZ + tid * STG_STRIDE;

        #pragma unroll
        for (int s = 0; s < SCH; ++s) {
            float mh[9], gh[9];
            #pragma unroll
            for (int j = 0; j < 3; ++j) {
                mh[j]     = M00 * h[j] + M01 * h[3+j] + M02 * h[6+j];
                mh[3 + j] = M10 * h[j] + M11 * h[3+j];
                mh[6 + j] = M20 * h[j] + M22 * h[6+j];
            }
            #pragma unroll
            for (int c = 0; c < 3; ++c)
                #pragma unroll
                for (int j = 0; j < 3; ++j)
                    gh[c*3+j] = gb3[j] + mh[c*3+0]*W9[j] + mh[c*3+1]*W9[3+j] + mh[c*3+2]*W9[6+j];
            #pragma unroll
            for (int c = 0; c < 3; ++c) {
                #pragma unroll
                for (int j = 0; j < 3; ++j) {
                    float g  = gh[c*3+j];
                    float r  = fast_sigmoid(xr[j] + g);
                    float z  = fast_sigmoid(xz[j] + g);
                    float ht = fast_tanh(xh[j] + r * g);
                    float hv = h[c*3+j];
                    h[c*3+j] = hv + z * (ht - hv);
                }
            }
            #pragma unroll
            for (int q = 0; q < 9; ++q) stw[s*9 + q] = h[q];
        }

        __syncthreads();   // 1-wave block: compiles to a cheap waitcnt fence

        // replica-split coalesced expansion: this wave does iters rep, rep+4, ...
        // covering f4 indices f = i*64 + tid over 64 rows x 33 f4 = 2112 total.
        const float* str = stage + (chunk & 1) * STG_SZ;
        const int c33 = chunk * ROW_F4;
        for (int i = rep; i < ROW_F4; i += REP) {
            int f  = i * TPB + tid;          // 0..2111
            int r  = f / 33;                 // row (chain within group)
            int j4 = f - r * 33;             // float4 index within row
            unsigned int tw = tabS[j4];
            const float* row = str + r * STG_STRIDE;
            float4 v;
            v.x = row[tw & 255u];
            v.y = row[(tw >> 8)  & 255u];
            v.z = row[(tw >> 16) & 255u];
            v.w = row[tw >> 24];
            out4[(size_t)(b0 + r) * 1650 + c33 + j4] = v;
        }
        // no trailing barrier: single-wave block, DS pipe is in-order per wave;
        // next chunk writes the other buffer.
    }
}

extern "C" void kernel_launch(void* const* d_in, const int* in_sizes, int n_in,
                              void* d_out, int out_size, void* d_ws, size_t ws_size,
                              hipStream_t stream) {
    const float* xp     = (const float*)d_in[0];
    const float* w_r_W  = (const float*)d_in[1];
    const float* w_r_b  = (const float*)d_in[2];
    const float* w_z_W  = (const float*)d_in[3];
    const float* w_z_b  = (const float*)d_in[4];
    const float* w_h_W  = (const float*)d_in[5];
    const float* w_h_b  = (const float*)d_in[6];
    const float* gcn_W  = (const float*)d_in[7];
    const float* gcn_b  = (const float*)d_in[8];
    float* outp = (float*)d_out;

    gcgru_kernel<<<GRID, TPB, 0, stream>>>(xp, w_r_W, w_r_b, w_z_W, w_z_b,
                                           w_h_W, w_h_b, gcn_W, gcn_b, outp);
}

// Round 3
// 488.407 us; speedup vs baseline: 1.1360x; 1.0999x over previous
//
#include <hip/hip_runtime.h>

// GraphConvGRU: B=16384, IN=32, HID=3, N=22 nodes, T=100 steps.
// Graph collapses to 3 node-equivalence classes -> per-chain state is 9 floats,
// 22x22 normalized adjacency reduces exactly to 3x3 (verified; R0/R1 passed,
// absmax 3.9e-3).
//
// R2 change: contiguous store ownership + longer runs.
//   R1 strided the f4 expansion across replicas (i += REP) -> every 528B
//   row-run split across 2 CUs/XCDs -> partial-line writebacks from
//   non-coherent L2s -> ~1.7 TB/s effective write BW (~250us kernel).
//   Now: replica rep owns rows [rep*16, rep*16+16) of its 64-chain group and
//   writes them entirely; SCH=4 doubles run length to 1056B. Every 128B line
//   has a single writer; runs extend chunk-to-chunk within the same wave.

#define TPB 64
#define REP 4
#define RPW 16                      // rows stored per replica = TPB/REP
#define NGRP (16384 / TPB)          // 256 chain-groups
#define GRID (NGRP * REP)           // 1024 blocks
#define T_TOTAL 100
#define SCH 4                       // steps per chunk
#define NCHUNK (T_TOTAL / SCH)      // 25
#define ROW_F4 (SCH * 66 / 4)       // 66 float4 per (row, chunk)
#define STG_STRIDE (SCH * 9 + 1)    // 37 floats per thread-row (odd: bank-friendly)
#define STG_SZ (TPB * STG_STRIDE)   // 2368 floats per buffer
#define F4_PER_REP (RPW * ROW_F4)   // 1056 f4 per replica per chunk

#if __has_builtin(__builtin_amdgcn_exp2f)
#define EXP2F __builtin_amdgcn_exp2f
#else
#define EXP2F exp2f
#endif
#if __has_builtin(__builtin_amdgcn_rcpf)
#define RCPF __builtin_amdgcn_rcpf
#else
#define RCPF(x) (1.0f / (x))
#endif

static __device__ __forceinline__ float fast_sigmoid(float x) {
    float e = EXP2F(-1.44269504f * x);
    return RCPF(1.0f + e);
}
static __device__ __forceinline__ float fast_tanh(float x) {
    float e = EXP2F(2.88539008f * x);          // exp(2x)
    return 1.0f - 2.0f * RCPF(1.0f + e);
}

__global__ __launch_bounds__(TPB) void gcgru_kernel(
    const float* __restrict__ x,
    const float* __restrict__ w_r_W, const float* __restrict__ w_r_b,
    const float* __restrict__ w_z_W, const float* __restrict__ w_z_b,
    const float* __restrict__ w_h_W, const float* __restrict__ w_h_b,
    const float* __restrict__ gcn_W, const float* __restrict__ gcn_b,
    float* __restrict__ out)
{
    __shared__ float wS[297];           // w_r_W[96], w_z_W[96], w_h_W[96], biases r/z/h [9]
    __shared__ float gwS[9];
    __shared__ float gbS[3];
    __shared__ unsigned int tabS[ROW_F4];   // per-f4 packed state-index table (66 entries)
    __shared__ float stage[2 * STG_SZ];     // double-buffered compact states

    const int tid = threadIdx.x;            // 0..63, chain within group
    const int rep = blockIdx.x & (REP - 1); // replica id 0..3
    const int b0  = (blockIdx.x >> 2) * TPB;
    const int row0 = rep * RPW;             // first row this replica stores

    // ---- one-time: stage weights + build expansion table ----
    for (int i = tid; i < 96; i += TPB) {
        wS[i]       = w_r_W[i];
        wS[96 + i]  = w_z_W[i];
        wS[192 + i] = w_h_W[i];
    }
    if (tid < 3) {
        wS[288 + tid] = w_r_b[tid];
        wS[291 + tid] = w_z_b[tid];
        wS[294 + tid] = w_h_b[tid];
        gbS[tid] = gcn_b[tid];
    }
    if (tid < 9) gwS[tid] = gcn_W[tid];
    {
        // cls3[k] = class(node k/3)*3 + k%3 for k in [0,66)
        static const unsigned char cls3[66] = {
            0,1,2, 3,4,5, 3,4,5, 6,7,8, 3,4,5, 3,4,5, 6,7,8, 3,4,5, 3,4,5,
            0,1,2, 3,4,5, 3,4,5, 6,7,8, 3,4,5, 3,4,5, 6,7,8, 3,4,5, 3,4,5,
            3,4,5, 3,4,5, 3,4,5, 3,4,5
        };
        for (int j4 = tid; j4 < ROW_F4; j4 += TPB) {
            unsigned int w = 0;
            #pragma unroll
            for (int u = 0; u < 4; ++u) {
                int jj = 4 * j4 + u;         // 0..SCH*66-1 within a chunk-row
                int tl = jj / 66;            // local step 0..SCH-1
                int k  = jj - 66 * tl;       // 0..65
                w |= (unsigned int)(tl * 9 + cls3[k]) << (8 * u);
            }
            tabS[j4] = w;
        }
    }
    __syncthreads();

    // ---- per-chain input projections: xr/xz/xh = x @ W + b ----
    float xv[32];
    {
        const float4* xp = reinterpret_cast<const float4*>(x + (size_t)(b0 + tid) * 32);
        #pragma unroll
        for (int i = 0; i < 8; ++i) {
            float4 v = xp[i];
            xv[4*i+0] = v.x; xv[4*i+1] = v.y; xv[4*i+2] = v.z; xv[4*i+3] = v.w;
        }
    }
    float xr[3], xz[3], xh[3];
    #pragma unroll
    for (int j = 0; j < 3; ++j) { xr[j] = wS[288+j]; xz[j] = wS[291+j]; xh[j] = wS[294+j]; }
    #pragma unroll
    for (int i = 0; i < 32; ++i) {
        float xi = xv[i];
        #pragma unroll
        for (int j = 0; j < 3; ++j) {
            xr[j] = fmaf(xi, wS[i*3+j],       xr[j]);
            xz[j] = fmaf(xi, wS[96 + i*3+j],  xz[j]);
            xh[j] = fmaf(xi, wS[192 + i*3+j], xh[j]);
        }
    }

    float W9[9], gb3[3];
    #pragma unroll
    for (int i = 0; i < 9; ++i) W9[i] = gwS[i];
    #pragma unroll
    for (int j = 0; j < 3; ++j) gb3[j] = gbS[j];

    // reduced symmetric-normalized adjacency (3 classes), exact:
    const float M00 = 0.0769230769f;   // 1/13
    const float M01 = 1.1094003925f;   // 4/sqrt(13)
    const float M02 = 0.4961389384f;   // 4/sqrt(65)
    const float M10 = 0.1386750491f;   // 1/(2 sqrt(13))
    const float M11 = 0.75f;
    const float M20 = 0.2480694691f;   // 2/sqrt(65)
    const float M22 = 0.6f;

    float h[9];
    #pragma unroll
    for (int i = 0; i < 9; ++i) h[i] = 0.0f;

    float4* out4 = reinterpret_cast<float4*>(out);

    for (int chunk = 0; chunk < NCHUNK; ++chunk) {
        float* stw = stage + (chunk & 1) * STG_SZ + tid * STG_STRIDE;

        #pragma unroll
        for (int s = 0; s < SCH; ++s) {
            float mh[9], gh[9];
            #pragma unroll
            for (int j = 0; j < 3; ++j) {
                mh[j]     = M00 * h[j] + M01 * h[3+j] + M02 * h[6+j];
                mh[3 + j] = M10 * h[j] + M11 * h[3+j];
                mh[6 + j] = M20 * h[j] + M22 * h[6+j];
            }
            #pragma unroll
            for (int c = 0; c < 3; ++c)
                #pragma unroll
                for (int j = 0; j < 3; ++j)
                    gh[c*3+j] = gb3[j] + mh[c*3+0]*W9[j] + mh[c*3+1]*W9[3+j] + mh[c*3+2]*W9[6+j];
            #pragma unroll
            for (int c = 0; c < 3; ++c) {
                #pragma unroll
                for (int j = 0; j < 3; ++j) {
                    float g  = gh[c*3+j];
                    float r  = fast_sigmoid(xr[j] + g);
                    float z  = fast_sigmoid(xz[j] + g);
                    float ht = fast_tanh(xh[j] + r * g);
                    float hv = h[c*3+j];
                    h[c*3+j] = hv + z * (ht - hv);
                }
            }
            #pragma unroll
            for (int q = 0; q < 9; ++q) stw[s*9 + q] = h[q];
        }

        __syncthreads();   // 1-wave block: cheap

        // contiguous-ownership expansion: this replica writes rows
        // [row0, row0+16) of the group, f-space contiguous -> every output
        // 128B line has a single writer, runs of 1056B extend chunk-to-chunk.
        const float* str = stage + (chunk & 1) * STG_SZ;
        const int cbase = chunk * ROW_F4;
        for (int i = 0; i < (F4_PER_REP + TPB - 1) / TPB; ++i) {
            int f = i * TPB + tid;           // 0..1055 within replica span
            if (f < F4_PER_REP) {
                int rl = f / ROW_F4;         // 0..15
                int j4 = f - rl * ROW_F4;    // 0..65
                int r  = row0 + rl;
                unsigned int tw = tabS[j4];
                const float* row = str + r * STG_STRIDE;
                float4 v;
                v.x = row[tw & 255u];
                v.y = row[(tw >> 8)  & 255u];
                v.z = row[(tw >> 16) & 255u];
                v.w = row[tw >> 24];
                out4[(size_t)(b0 + r) * 1650 + cbase + j4] = v;
            }
        }
        // no trailing barrier: single-wave block; next chunk uses other buffer.
    }
}

extern "C" void kernel_launch(void* const* d_in, const int* in_sizes, int n_in,
                              void* d_out, int out_size, void* d_ws, size_t ws_size,
                              hipStream_t stream) {
    const float* xp     = (const float*)d_in[0];
    const float* w_r_W  = (const float*)d_in[1];
    const float* w_r_b  = (const float*)d_in[2];
    const float* w_z_W  = (const float*)d_in[3];
    const float* w_z_b  = (const float*)d_in[4];
    const float* w_h_W  = (const float*)d_in[5];
    const float* w_h_b  = (const float*)d_in[6];
    const float* gcn_W  = (const float*)d_in[7];
    const float* gcn_b  = (const float*)d_in[8];
    float* outp = (float*)d_out;

    gcgru_kernel<<<GRID, TPB, 0, stream>>>(xp, w_r_W, w_r_b, w_z_W, w_z_b,
                                           w_h_W, w_h_b, gcn_W, gcn_b, outp);
}